// Round 23
// baseline (153.456 us; speedup 1.0000x reference)
//
#include <hip/hip_runtime.h>

typedef __attribute__((ext_vector_type(4))) float f32x4;
typedef __attribute__((ext_vector_type(8))) short s16x8;

#define NB 128      // batch
#define NA 100      // atoms (N)
#define KF 32       // INNER
#define NF 33       // F = INNER+1
#define NU 512      // UNITS
#define ND 3        // DEPTH
#define LOG2E 1.4426950408889634f

#define SZ_S0    (NB * NA * KF)
#define SZ_BONDS (NB * NA * NA)

// native gfx950 transcendentals (base-2)
#define EXP2F(x) __builtin_amdgcn_exp2f(x)
#define LOG2F(x) __builtin_amdgcn_logf(x)

__device__ __forceinline__ unsigned short f2bf(float f) {
    unsigned int u = __float_as_uint(f);
    u = (u + 0x7fffu + ((u >> 16) & 1u)) >> 16;      // RNE
    return (unsigned short)u;
}
__device__ __forceinline__ float bf2f(unsigned short h) {
    return __uint_as_float(((unsigned int)h) << 16);
}
// pack two nonneg f32 into bf16 pair (round-half-up)
__device__ __forceinline__ unsigned int pack_bf16(float a, float b) {
    const unsigned int ua = (__float_as_uint(a) + 0x8000u) >> 16;
    const unsigned int ub = (__float_as_uint(b) + 0x8000u) & 0xffff0000u;
    return ua | ub;
}

// ---------------------------------------------------------------------------
// Phase 1: per (b,i): S0 row-sum, attrAll[b][0][i][:], bonds. Coalesced f32.
// (12800-block flat grid -- R22 proved collapsing this parallelism loses 4x.)
// ---------------------------------------------------------------------------
__global__ __launch_bounds__(256) void p1_reduce(const float* __restrict__ x,
    float* __restrict__ S0, float* __restrict__ attrAll, float* __restrict__ bonds)
{
    const int blk = blockIdx.x;            // b*NA + i
    const int b   = blk / NA;
    const int i   = blk % NA;
    const int t   = threadIdx.x;

    __shared__ float lds[NA * NF];         // 13.2 KB
    __shared__ float red[8][KF];

    const float4* row4 = (const float4*)(x + (size_t)blk * (NA * NF));
    float4* lds4 = (float4*)lds;
    for (int idx = t; idx < (NA * NF) / 4; idx += 256) lds4[idx] = row4[idx];
    __syncthreads();

    const int g = t >> 5;                  // 0..7
    const int f = t & 31;
    float p0 = 0.f, p1 = 0.f;
    for (int j = g; j + 8 < NA; j += 16) {
        p0 += lds[j * NF + f];
        p1 += lds[(j + 8) * NF + f];
    }
    if (g < 4) p0 += lds[(96 + g) * NF + f];   // tail rows 96..99
    red[g][f] = p0 + p1;
    __syncthreads();

    if (t < KF) {
        float s = 0.f;
#pragma unroll
        for (int gg = 0; gg < 8; ++gg) s += red[gg][t];
        S0[(size_t)blk * KF + t] = s;
    } else if (t >= 64 && t < 64 + KF) {
        attrAll[(size_t)b * (ND + 1) * NA * KF + (size_t)i * KF + (t - 64)] = lds[i * NF + (t - 64)];
    } else if (t >= 128 && t < 128 + NA) {
        const int j = t - 128;
        bonds[(size_t)blk * NA + j] = lds[j * NF + KF];
    }
}

// ---------------------------------------------------------------------------
// Phase 2a (+fused pW): blocks 0..255 = recurrence halves (b, half);
// blocks 256..271 = pW (W_output*LOG2E -> bf16 hi/lo B-fragments).
// ---------------------------------------------------------------------------
#define NAH 50                        // rows per half-block
#define ELH (NAH * KF)                // 1600 elements per half
__global__ __launch_bounds__(256) void p2a_recur(
    const float* __restrict__ S0, const float* __restrict__ bonds,
    const float* __restrict__ W_inner, const float* __restrict__ b_inner,
    float* __restrict__ attrAll,
    const float* __restrict__ W_output,
    unsigned short* __restrict__ WBh, unsigned short* __restrict__ WBl)
{
    const int blk = blockIdx.x;
    const int t   = threadIdx.x;

    if (blk >= NB * 2) {
        const int pb = blk - NB * 2;                 // 0..15
        const int base = pb * 4096;
        for (int j = t; j < 4096; j += 256) {
            const int i = base + j;                      // 0..65535
            const int d = i >> 14, rem = i & 16383, k = rem >> 9, col = rem & 511;
            const float v = W_output[(size_t)d * (KF * NU) + (size_t)k * NU + col] * LOG2E;
            const unsigned short hi = f2bf(v);
            const unsigned short lo = f2bf(v - bf2f(hi));
            const int dst = d * 16384 + (col >> 4) * 512 + (k >> 3) * 128 + (col & 15) * 8 + (k & 7);
            WBh[dst] = hi;
            WBl[dst] = lo;
        }
        return;
    }

    __shared__ float S[ELH];          // 6.4 KB
    __shared__ float attr[ELH];
    __shared__ float rs[NAH];

    const int half = blk & 1;
    const int b    = blk >> 1;
    const int f    = t & 31;

    const float4* s4 = (const float4*)(S0 + (size_t)b * NA * KF + half * ELH);
    const float4* a4 = (const float4*)(attrAll + (size_t)b * (ND + 1) * NA * KF + half * ELH);
    for (int idx = t; idx < ELH / 4; idx += 256) {
        ((float4*)S)[idx]    = s4[idx];
        ((float4*)attr)[idx] = a4[idx];
    }
    if (t < NAH) {
        const int i = half * NAH + t;             // global row
        const float* bb = bonds + (size_t)b * NA * NA + i;
        float c0=0.f,c1=0.f,c2=0.f,c3=0.f,c4=0.f,c5=0.f,c6=0.f,c7=0.f;
        int j = 0;
        for (; j + 8 <= NA; j += 8) {
            c0 += bb[(j+0)*NA]; c1 += bb[(j+1)*NA];
            c2 += bb[(j+2)*NA]; c3 += bb[(j+3)*NA];
            c4 += bb[(j+4)*NA]; c5 += bb[(j+5)*NA];
            c6 += bb[(j+6)*NA]; c7 += bb[(j+7)*NA];
        }
        for (; j < NA; ++j) c0 += bb[j*NA];
        rs[t] = 1.f + (((c0+c1)+(c2+c3))+((c4+c5)+(c6+c7)));
    }
    __syncthreads();

    float* attrDst = attrAll + (size_t)b * (ND + 1) * NA * KF + half * ELH;

    for (int d = 1; d <= ND; ++d) {
        float Wc[KF];
        const float* Wd = W_inner + d * KF * KF + f;
#pragma unroll
        for (int k = 0; k < KF; ++k) Wc[k] = Wd[k * KF];
        const float bi = b_inner[d * KF + f];

        float core[7];
#pragma unroll
        for (int it = 0; it < 7; ++it) {
            const int idx = t + it * 256;
            if (idx < ELH) {
                const int row = idx >> 5;
                const float4* Sr4 = (const float4*)(S + row * KF);   // broadcast b128
                float acc = bi;
#pragma unroll
                for (int q = 0; q < 8; ++q) {
                    const float4 sv = Sr4[q];
                    acc += sv.x * Wc[4*q] + sv.y * Wc[4*q+1]
                         + sv.z * Wc[4*q+2] + sv.w * Wc[4*q+3];
                }
                core[it] = acc;
            }
        }
        __syncthreads();
#pragma unroll
        for (int it = 0; it < 7; ++it) {
            const int idx = t + it * 256;
            if (idx < ELH) {
                const int row = idx >> 5;
                const float cc  = core[it];
                const float old = attr[idx];
                attr[idx] = cc;
                S[idx] += rs[row] * (cc - old);
                attrDst[(size_t)d * NA * KF + idx] = cc;
            }
        }
        __syncthreads();
    }
}

// ---------------------------------------------------------------------------
// Phase 2b: block=(b,d), 448 thr = 7 waves. As R21 but ALL sweep loops fully
// unrolled: tt becomes compile-time -> LDS reads use immediate offsets,
// killing the per-tile VALU address arithmetic (the theorized ~2x VALU bloat).
// WBh in LDS, WBl from global (L2), base-2 exp2, eP[32]. LDS 49152 B.
// ---------------------------------------------------------------------------
__global__ __launch_bounds__(448, 4) void p2b_mfma(
    const float* __restrict__ attrAll,
    const unsigned short* __restrict__ WBh_g, const unsigned short* __restrict__ WBl_g,
    const float* __restrict__ b_output, float* __restrict__ fpPart)
{
    extern __shared__ unsigned char smraw[];
    unsigned short* WBh  = (unsigned short*)smraw;        // 32768 B
    unsigned short* aAh  = WBh + 16384;                   //  7168 B
    unsigned short* aAl  = aAh + 3584;                    //  7168 B
    float*          biasL= (float*)(aAl + 3584);          //  2048 B (total 49152)
    float*          fpw  = (float*)aAh;                   // overlay after frag loads

    const int blk = blockIdx.x;
    const int b   = blk & (NB - 1);
    const int d   = blk >> 7;
    const int t   = threadIdx.x;
    const int l   = t & 63;
    const int w   = t >> 6;                               // 0..6

    // stage W-hi (coalesced) into LDS; bias * LOG2E
    for (int i = t; i < 2048; i += 448) ((float4*)WBh)[i] = ((const float4*)WBh_g)[d * 2048 + i];
    for (int i = t; i < NU; i += 448)   biasL[i] = b_output[d * NU + i] * LOG2E;

    // stage attr -> bf16 hi/lo A-fragments in LDS (112 rows x 32 k, pad=0)
    const float* A = attrAll + ((size_t)b * (ND + 1) + d) * (NA * KF);
    for (int i = t; i < 3584; i += 448) {
        const int gr = i >> 5, k = i & 31;
        const float v = (gr < NA) ? A[gr * KF + k] : 0.f;
        const unsigned short hi = f2bf(v);
        const unsigned short lo = f2bf(v - bf2f(hi));
        const int dst = ((gr >> 4) * 4 + (k >> 3)) * 128 + (gr & 15) * 8 + (k & 7);
        aAh[dst] = hi;
        aAl[dst] = lo;
    }
    __syncthreads();

    // A-fragments for this wave's row-tile (1 contiguous b128 each)
    const int aoff = (w * 4 + (l >> 4)) * 128 + (l & 15) * 8;
    const s16x8 ah = *(const s16x8*)&aAh[aoff];
    const s16x8 al = *(const s16x8*)&aAl[aoff];
    __syncthreads();   // aAh/aAl dead; fpw may overwrite after sweeps

    const int laneoff = (l >> 4) * 128 + (l & 15) * 8;
    const unsigned short* wblg = WBl_g + d * 16384;       // lo-frags straight from L2
    const f32x4 z = {0.f, 0.f, 0.f, 0.f};

    // ---- sweep A: row max, hi-only MFMA (FULL unroll: imm offsets) ---------
    float m[4] = {-1e30f, -1e30f, -1e30f, -1e30f};
#pragma unroll
    for (int tt = 0; tt < 32; ++tt) {
        const s16x8 bh = *(const s16x8*)&WBh[tt * 512 + laneoff];
        const f32x4 c = __builtin_amdgcn_mfma_f32_16x16x32_bf16(ah, bh, z, 0, 0, 0);
        const float bias = biasL[tt * 16 + (l & 15)];
#pragma unroll
        for (int r = 0; r < 4; ++r) m[r] = fmaxf(m[r], c[r] + bias);
    }
#pragma unroll
    for (int off = 1; off <= 8; off <<= 1)
#pragma unroll
        for (int r = 0; r < 4; ++r) m[r] = fmaxf(m[r], __shfl_xor(m[r], off, 64));

    // ---- sweep B1: tiles 0..15, exp2-sum only (FULL unroll) ----------------
    float s[4] = {0.f, 0.f, 0.f, 0.f};
#pragma unroll
    for (int tt = 0; tt < 16; ++tt) {
        const s16x8 bh = *(const s16x8*)&WBh[tt * 512 + laneoff];
        const s16x8 bl = *(const s16x8*)&wblg[tt * 512 + laneoff];
        f32x4 c = __builtin_amdgcn_mfma_f32_16x16x32_bf16(ah, bh, z, 0, 0, 0);
        c = __builtin_amdgcn_mfma_f32_16x16x32_bf16(ah, bl, c, 0, 0, 0);
        c = __builtin_amdgcn_mfma_f32_16x16x32_bf16(al, bh, c, 0, 0, 0);
        const float bias = biasL[tt * 16 + (l & 15)];
#pragma unroll
        for (int r = 0; r < 4; ++r)
            s[r] += EXP2F(c[r] + bias - m[r]);
    }

    // ---- sweep B2: tiles 16..31, exp2-sum + eP[32] pack --------------------
    unsigned int eP[32];
#pragma unroll
    for (int tt = 16; tt < 32; ++tt) {
        const s16x8 bh = *(const s16x8*)&WBh[tt * 512 + laneoff];
        const s16x8 bl = *(const s16x8*)&wblg[tt * 512 + laneoff];
        f32x4 c = __builtin_amdgcn_mfma_f32_16x16x32_bf16(ah, bh, z, 0, 0, 0);
        c = __builtin_amdgcn_mfma_f32_16x16x32_bf16(ah, bl, c, 0, 0, 0);
        c = __builtin_amdgcn_mfma_f32_16x16x32_bf16(al, bh, c, 0, 0, 0);
        const float bias = biasL[tt * 16 + (l & 15)];
        const float e0 = EXP2F(c[0] + bias - m[0]);
        const float e1 = EXP2F(c[1] + bias - m[1]);
        const float e2 = EXP2F(c[2] + bias - m[2]);
        const float e3 = EXP2F(c[3] + bias - m[3]);
        s[0] += e0; s[1] += e1; s[2] += e2; s[3] += e3;
        eP[(tt - 16) * 2]     = pack_bf16(e0, e1);
        eP[(tt - 16) * 2 + 1] = pack_bf16(e2, e3);
    }
#pragma unroll
    for (int off = 1; off <= 8; off <<= 1)
#pragma unroll
        for (int r = 0; r < 4; ++r) s[r] += __shfl_xor(s[r], off, 64);

    float K[4], inv[4];
#pragma unroll
    for (int r = 0; r < 4; ++r) {
        const int grow = w * 16 + (l >> 4) * 4 + r;
        const bool ok = (grow < NA);
        K[r]   = ok ? (m[r] + LOG2F(s[r])) : 1e30f;   // exp2(c-K) = e/s
        inv[r] = ok ? (1.f / s[r]) : 0.f;
    }

    // ---- sweep C1: tiles 0..15 recompute (FULL unroll) ---------------------
#pragma unroll
    for (int tt = 0; tt < 16; ++tt) {
        const s16x8 bh = *(const s16x8*)&WBh[tt * 512 + laneoff];
        const s16x8 bl = *(const s16x8*)&wblg[tt * 512 + laneoff];
        f32x4 c = __builtin_amdgcn_mfma_f32_16x16x32_bf16(ah, bh, z, 0, 0, 0);
        c = __builtin_amdgcn_mfma_f32_16x16x32_bf16(ah, bl, c, 0, 0, 0);
        c = __builtin_amdgcn_mfma_f32_16x16x32_bf16(al, bh, c, 0, 0, 0);
        const float bias = biasL[tt * 16 + (l & 15)];
        float f = 0.f;
#pragma unroll
        for (int r = 0; r < 4; ++r)
            f += EXP2F(c[r] + bias - K[r]);
        f += __shfl_xor(f, 16, 64);
        f += __shfl_xor(f, 32, 64);
        if (l < 16) fpw[w * NU + tt * 16 + l] = f;
    }
    // ---- sweep C2: tiles 16..31 from registers -----------------------------
#pragma unroll
    for (int tt = 16; tt < 32; ++tt) {
        const unsigned int p01 = eP[(tt - 16) * 2];
        const unsigned int p23 = eP[(tt - 16) * 2 + 1];
        float f = __uint_as_float(p01 << 16)         * inv[0]
                + __uint_as_float(p01 & 0xffff0000u) * inv[1]
                + __uint_as_float(p23 << 16)         * inv[2]
                + __uint_as_float(p23 & 0xffff0000u) * inv[3];
        f += __shfl_xor(f, 16, 64);
        f += __shfl_xor(f, 32, 64);
        if (l < 16) fpw[w * NU + tt * 16 + l] = f;
    }
    __syncthreads();

    for (int u = t; u < NU; u += 448) {
        float sacc = 0.f;
#pragma unroll
        for (int ww = 0; ww < 7; ++ww) sacc += fpw[ww * NU + u];
        fpPart[((size_t)d * NB + b) * NU + u] = sacc;
    }
}

// ---------------------------------------------------------------------------
// Phase 2c: out[b][u] = sum_d fpPart[d][b][u]
// ---------------------------------------------------------------------------
__global__ __launch_bounds__(512) void p2c_out(const float* __restrict__ fpPart,
                                               float* __restrict__ out)
{
    const int b = blockIdx.x, t = threadIdx.x;
    float s = 0.f;
#pragma unroll
    for (int d = 0; d <= ND; ++d) s += fpPart[((size_t)d * NB + b) * NU + t];
    out[(size_t)b * NU + t] = s;
}

// ---------------------------------------------------------------------------
extern "C" void kernel_launch(void* const* d_in, const int* in_sizes, int n_in,
                              void* d_out, int out_size, void* d_ws, size_t ws_size,
                              hipStream_t stream) {
    (void)in_sizes; (void)n_in; (void)out_size; (void)ws_size;
    const float* x        = (const float*)d_in[0];
    const float* W_inner  = (const float*)d_in[1];
    const float* b_inner  = (const float*)d_in[2];
    const float* W_output = (const float*)d_in[3];
    const float* b_output = (const float*)d_in[4];
    float* out = (float*)d_out;

    float* S0      = (float*)d_ws;                         // 409600 f32
    float* bonds   = S0 + SZ_S0;                           // 1280000 f32
    float* attrAll = bonds + SZ_BONDS;                     // 1638400 f32
    unsigned short* WBh = (unsigned short*)(attrAll + (size_t)NB * (ND + 1) * NA * KF);
    unsigned short* WBl = WBh + 65536;
    float* fpPart = bonds;                                 // overlay (bonds dead after p2a)

    p1_reduce<<<NB * NA, 256, 0, stream>>>(x, S0, attrAll, bonds);
    p2a_recur<<<NB * 2 + 16, 256, 0, stream>>>(S0, bonds, W_inner, b_inner, attrAll,
                                               W_output, WBh, WBl);

    const size_t smemB = 49152;                            // 48 KB -> 3 blocks/CU
    hipFuncSetAttribute(reinterpret_cast<const void*>(p2b_mfma),
                        hipFuncAttributeMaxDynamicSharedMemorySize, (int)smemB);
    p2b_mfma<<<NB * (ND + 1), 448, smemB, stream>>>(attrAll, WBh, WBl, b_output, fpPart);
    p2c_out<<<NB, 512, 0, stream>>>(fpPart, out);
}

// Round 24
// 67.563 us; speedup vs baseline: 2.2713x; 2.2713x over previous
//
#include <hip/hip_runtime.h>

typedef __attribute__((ext_vector_type(4))) float f32x4;
typedef __attribute__((ext_vector_type(8))) short s16x8;

#define NB 128      // batch
#define NA 100      // atoms (N)
#define KF 32       // INNER
#define NF 33       // F = INNER+1
#define NU 512      // UNITS
#define ND 3        // DEPTH
#define LOG2E 1.4426950408889634f

#define SZ_S0    (NB * NA * KF)
#define SZ_BONDS (NB * NA * NA)

// native gfx950 transcendentals (base-2)
#define EXP2F(x) __builtin_amdgcn_exp2f(x)
#define LOG2F(x) __builtin_amdgcn_logf(x)

__device__ __forceinline__ unsigned short f2bf(float f) {
    unsigned int u = __float_as_uint(f);
    u = (u + 0x7fffu + ((u >> 16) & 1u)) >> 16;      // RNE
    return (unsigned short)u;
}
__device__ __forceinline__ float bf2f(unsigned short h) {
    return __uint_as_float(((unsigned int)h) << 16);
}
// pack two nonneg f32 into bf16 pair (round-half-up)
__device__ __forceinline__ unsigned int pack_bf16(float a, float b) {
    const unsigned int ua = (__float_as_uint(a) + 0x8000u) >> 16;
    const unsigned int ub = (__float_as_uint(b) + 0x8000u) & 0xffff0000u;
    return ua | ub;
}

// ---------------------------------------------------------------------------
// Phase 1: per (b,i): S0 row-sum, attrAll[b][0][i][:], bonds. Coalesced f32.
// ---------------------------------------------------------------------------
__global__ __launch_bounds__(256) void p1_reduce(const float* __restrict__ x,
    float* __restrict__ S0, float* __restrict__ attrAll, float* __restrict__ bonds)
{
    const int blk = blockIdx.x;            // b*NA + i
    const int b   = blk / NA;
    const int i   = blk % NA;
    const int t   = threadIdx.x;

    __shared__ float lds[NA * NF];         // 13.2 KB
    __shared__ float red[8][KF];

    const float4* row4 = (const float4*)(x + (size_t)blk * (NA * NF));
    float4* lds4 = (float4*)lds;
    for (int idx = t; idx < (NA * NF) / 4; idx += 256) lds4[idx] = row4[idx];
    __syncthreads();

    const int g = t >> 5;                  // 0..7
    const int f = t & 31;
    float p0 = 0.f, p1 = 0.f;
    for (int j = g; j + 8 < NA; j += 16) {
        p0 += lds[j * NF + f];
        p1 += lds[(j + 8) * NF + f];
    }
    if (g < 4) p0 += lds[(96 + g) * NF + f];   // tail rows 96..99
    red[g][f] = p0 + p1;
    __syncthreads();

    if (t < KF) {
        float s = 0.f;
#pragma unroll
        for (int gg = 0; gg < 8; ++gg) s += red[gg][t];
        S0[(size_t)blk * KF + t] = s;
    } else if (t >= 64 && t < 64 + KF) {
        attrAll[(size_t)b * (ND + 1) * NA * KF + (size_t)i * KF + (t - 64)] = lds[i * NF + (t - 64)];
    } else if (t >= 128 && t < 128 + NA) {
        const int j = t - 128;
        bonds[(size_t)blk * NA + j] = lds[j * NF + KF];
    }
}

// ---------------------------------------------------------------------------
// Phase 2a (+fused pW): blocks 0..255 = recurrence halves (b, half);
// blocks 256..271 = pW (W_output*LOG2E -> bf16 hi/lo B-fragments).
// ---------------------------------------------------------------------------
#define NAH 50                        // rows per half-block
#define ELH (NAH * KF)                // 1600 elements per half
__global__ __launch_bounds__(256) void p2a_recur(
    const float* __restrict__ S0, const float* __restrict__ bonds,
    const float* __restrict__ W_inner, const float* __restrict__ b_inner,
    float* __restrict__ attrAll,
    const float* __restrict__ W_output,
    unsigned short* __restrict__ WBh, unsigned short* __restrict__ WBl)
{
    const int blk = blockIdx.x;
    const int t   = threadIdx.x;

    if (blk >= NB * 2) {
        const int pb = blk - NB * 2;                 // 0..15
        const int base = pb * 4096;
        for (int j = t; j < 4096; j += 256) {
            const int i = base + j;                      // 0..65535
            const int d = i >> 14, rem = i & 16383, k = rem >> 9, col = rem & 511;
            const float v = W_output[(size_t)d * (KF * NU) + (size_t)k * NU + col] * LOG2E;
            const unsigned short hi = f2bf(v);
            const unsigned short lo = f2bf(v - bf2f(hi));
            const int dst = d * 16384 + (col >> 4) * 512 + (k >> 3) * 128 + (col & 15) * 8 + (k & 7);
            WBh[dst] = hi;
            WBl[dst] = lo;
        }
        return;
    }

    __shared__ float S[ELH];          // 6.4 KB
    __shared__ float attr[ELH];
    __shared__ float rs[NAH];

    const int half = blk & 1;
    const int b    = blk >> 1;
    const int f    = t & 31;

    const float4* s4 = (const float4*)(S0 + (size_t)b * NA * KF + half * ELH);
    const float4* a4 = (const float4*)(attrAll + (size_t)b * (ND + 1) * NA * KF + half * ELH);
    for (int idx = t; idx < ELH / 4; idx += 256) {
        ((float4*)S)[idx]    = s4[idx];
        ((float4*)attr)[idx] = a4[idx];
    }
    if (t < NAH) {
        const int i = half * NAH + t;             // global row
        const float* bb = bonds + (size_t)b * NA * NA + i;
        float c0=0.f,c1=0.f,c2=0.f,c3=0.f,c4=0.f,c5=0.f,c6=0.f,c7=0.f;
        int j = 0;
        for (; j + 8 <= NA; j += 8) {
            c0 += bb[(j+0)*NA]; c1 += bb[(j+1)*NA];
            c2 += bb[(j+2)*NA]; c3 += bb[(j+3)*NA];
            c4 += bb[(j+4)*NA]; c5 += bb[(j+5)*NA];
            c6 += bb[(j+6)*NA]; c7 += bb[(j+7)*NA];
        }
        for (; j < NA; ++j) c0 += bb[j*NA];
        rs[t] = 1.f + (((c0+c1)+(c2+c3))+((c4+c5)+(c6+c7)));
    }
    __syncthreads();

    float* attrDst = attrAll + (size_t)b * (ND + 1) * NA * KF + half * ELH;

    for (int d = 1; d <= ND; ++d) {
        float Wc[KF];
        const float* Wd = W_inner + d * KF * KF + f;
#pragma unroll
        for (int k = 0; k < KF; ++k) Wc[k] = Wd[k * KF];
        const float bi = b_inner[d * KF + f];

        float core[7];
#pragma unroll
        for (int it = 0; it < 7; ++it) {
            const int idx = t + it * 256;
            if (idx < ELH) {
                const int row = idx >> 5;
                const float4* Sr4 = (const float4*)(S + row * KF);   // broadcast b128
                float acc = bi;
#pragma unroll
                for (int q = 0; q < 8; ++q) {
                    const float4 sv = Sr4[q];
                    acc += sv.x * Wc[4*q] + sv.y * Wc[4*q+1]
                         + sv.z * Wc[4*q+2] + sv.w * Wc[4*q+3];
                }
                core[it] = acc;
            }
        }
        __syncthreads();
#pragma unroll
        for (int it = 0; it < 7; ++it) {
            const int idx = t + it * 256;
            if (idx < ELH) {
                const int row = idx >> 5;
                const float cc  = core[it];
                const float old = attr[idx];
                attr[idx] = cc;
                S[idx] += rs[row] * (cc - old);
                attrDst[(size_t)d * NA * KF + idx] = cc;
            }
        }
        __syncthreads();
    }
}

// ---------------------------------------------------------------------------
// Phase 2b (R21 exact): block=(b,d), 448 thr = 7 waves. WBh in LDS, WBl from
// global (L2-resident), base-2 exp2, eP[32] half-registers, PARTIAL unrolls
// (unroll 2/4 -- full unroll spills: R23 measured 197MB scratch WRITE_SIZE).
// Dynamic LDS 49152 B -> 3 blocks/CU.
// ---------------------------------------------------------------------------
__global__ __launch_bounds__(448, 4) void p2b_mfma(
    const float* __restrict__ attrAll,
    const unsigned short* __restrict__ WBh_g, const unsigned short* __restrict__ WBl_g,
    const float* __restrict__ b_output, float* __restrict__ fpPart)
{
    extern __shared__ unsigned char smraw[];
    unsigned short* WBh  = (unsigned short*)smraw;        // 32768 B
    unsigned short* aAh  = WBh + 16384;                   //  7168 B
    unsigned short* aAl  = aAh + 3584;                    //  7168 B
    float*          biasL= (float*)(aAl + 3584);          //  2048 B (total 49152)
    float*          fpw  = (float*)aAh;                   // overlay after frag loads

    const int blk = blockIdx.x;
    const int b   = blk & (NB - 1);
    const int d   = blk >> 7;
    const int t   = threadIdx.x;
    const int l   = t & 63;
    const int w   = t >> 6;                               // 0..6

    // stage W-hi (coalesced) into LDS; bias * LOG2E
    for (int i = t; i < 2048; i += 448) ((float4*)WBh)[i] = ((const float4*)WBh_g)[d * 2048 + i];
    for (int i = t; i < NU; i += 448)   biasL[i] = b_output[d * NU + i] * LOG2E;

    // stage attr -> bf16 hi/lo A-fragments in LDS (112 rows x 32 k, pad=0)
    const float* A = attrAll + ((size_t)b * (ND + 1) + d) * (NA * KF);
    for (int i = t; i < 3584; i += 448) {
        const int gr = i >> 5, k = i & 31;
        const float v = (gr < NA) ? A[gr * KF + k] : 0.f;
        const unsigned short hi = f2bf(v);
        const unsigned short lo = f2bf(v - bf2f(hi));
        const int dst = ((gr >> 4) * 4 + (k >> 3)) * 128 + (gr & 15) * 8 + (k & 7);
        aAh[dst] = hi;
        aAl[dst] = lo;
    }
    __syncthreads();

    // A-fragments for this wave's row-tile (1 contiguous b128 each)
    const int aoff = (w * 4 + (l >> 4)) * 128 + (l & 15) * 8;
    const s16x8 ah = *(const s16x8*)&aAh[aoff];
    const s16x8 al = *(const s16x8*)&aAl[aoff];
    __syncthreads();   // aAh/aAl dead; fpw may overwrite after sweeps

    const int laneoff = (l >> 4) * 128 + (l & 15) * 8;
    const unsigned short* wblg = WBl_g + d * 16384;       // lo-frags straight from L2
    const f32x4 z = {0.f, 0.f, 0.f, 0.f};

    // ---- sweep A: row max, hi-only MFMA ------------------------------------
    float m[4] = {-1e30f, -1e30f, -1e30f, -1e30f};
#pragma unroll 4
    for (int tt = 0; tt < 32; ++tt) {
        const s16x8 bh = *(const s16x8*)&WBh[tt * 512 + laneoff];
        const f32x4 c = __builtin_amdgcn_mfma_f32_16x16x32_bf16(ah, bh, z, 0, 0, 0);
        const float bias = biasL[tt * 16 + (l & 15)];
#pragma unroll
        for (int r = 0; r < 4; ++r) m[r] = fmaxf(m[r], c[r] + bias);
    }
#pragma unroll
    for (int off = 1; off <= 8; off <<= 1)
#pragma unroll
        for (int r = 0; r < 4; ++r) m[r] = fmaxf(m[r], __shfl_xor(m[r], off, 64));

    // ---- sweep B1: tiles 0..15, exp2-sum only ------------------------------
    float s[4] = {0.f, 0.f, 0.f, 0.f};
#pragma unroll 2
    for (int tt = 0; tt < 16; ++tt) {
        const s16x8 bh = *(const s16x8*)&WBh[tt * 512 + laneoff];
        const s16x8 bl = *(const s16x8*)&wblg[tt * 512 + laneoff];
        f32x4 c = __builtin_amdgcn_mfma_f32_16x16x32_bf16(ah, bh, z, 0, 0, 0);
        c = __builtin_amdgcn_mfma_f32_16x16x32_bf16(ah, bl, c, 0, 0, 0);
        c = __builtin_amdgcn_mfma_f32_16x16x32_bf16(al, bh, c, 0, 0, 0);
        const float bias = biasL[tt * 16 + (l & 15)];
#pragma unroll
        for (int r = 0; r < 4; ++r)
            s[r] += EXP2F(c[r] + bias - m[r]);
    }

    // ---- sweep B2: tiles 16..31, exp2-sum + eP[32] pack --------------------
    unsigned int eP[32];
#pragma unroll
    for (int tt = 16; tt < 32; ++tt) {
        const s16x8 bh = *(const s16x8*)&WBh[tt * 512 + laneoff];
        const s16x8 bl = *(const s16x8*)&wblg[tt * 512 + laneoff];
        f32x4 c = __builtin_amdgcn_mfma_f32_16x16x32_bf16(ah, bh, z, 0, 0, 0);
        c = __builtin_amdgcn_mfma_f32_16x16x32_bf16(ah, bl, c, 0, 0, 0);
        c = __builtin_amdgcn_mfma_f32_16x16x32_bf16(al, bh, c, 0, 0, 0);
        const float bias = biasL[tt * 16 + (l & 15)];
        const float e0 = EXP2F(c[0] + bias - m[0]);
        const float e1 = EXP2F(c[1] + bias - m[1]);
        const float e2 = EXP2F(c[2] + bias - m[2]);
        const float e3 = EXP2F(c[3] + bias - m[3]);
        s[0] += e0; s[1] += e1; s[2] += e2; s[3] += e3;
        eP[(tt - 16) * 2]     = pack_bf16(e0, e1);
        eP[(tt - 16) * 2 + 1] = pack_bf16(e2, e3);
    }
#pragma unroll
    for (int off = 1; off <= 8; off <<= 1)
#pragma unroll
        for (int r = 0; r < 4; ++r) s[r] += __shfl_xor(s[r], off, 64);

    float K[4], inv[4];
#pragma unroll
    for (int r = 0; r < 4; ++r) {
        const int grow = w * 16 + (l >> 4) * 4 + r;
        const bool ok = (grow < NA);
        K[r]   = ok ? (m[r] + LOG2F(s[r])) : 1e30f;   // exp2(c-K) = e/s
        inv[r] = ok ? (1.f / s[r]) : 0.f;
    }

    // ---- sweep C1: tiles 0..15 recompute -----------------------------------
#pragma unroll 2
    for (int tt = 0; tt < 16; ++tt) {
        const s16x8 bh = *(const s16x8*)&WBh[tt * 512 + laneoff];
        const s16x8 bl = *(const s16x8*)&wblg[tt * 512 + laneoff];
        f32x4 c = __builtin_amdgcn_mfma_f32_16x16x32_bf16(ah, bh, z, 0, 0, 0);
        c = __builtin_amdgcn_mfma_f32_16x16x32_bf16(ah, bl, c, 0, 0, 0);
        c = __builtin_amdgcn_mfma_f32_16x16x32_bf16(al, bh, c, 0, 0, 0);
        const float bias = biasL[tt * 16 + (l & 15)];
        float f = 0.f;
#pragma unroll
        for (int r = 0; r < 4; ++r)
            f += EXP2F(c[r] + bias - K[r]);
        f += __shfl_xor(f, 16, 64);
        f += __shfl_xor(f, 32, 64);
        if (l < 16) fpw[w * NU + tt * 16 + l] = f;
    }
    // ---- sweep C2: tiles 16..31 from registers -----------------------------
#pragma unroll
    for (int tt = 16; tt < 32; ++tt) {
        const unsigned int p01 = eP[(tt - 16) * 2];
        const unsigned int p23 = eP[(tt - 16) * 2 + 1];
        float f = __uint_as_float(p01 << 16)         * inv[0]
                + __uint_as_float(p01 & 0xffff0000u) * inv[1]
                + __uint_as_float(p23 << 16)         * inv[2]
                + __uint_as_float(p23 & 0xffff0000u) * inv[3];
        f += __shfl_xor(f, 16, 64);
        f += __shfl_xor(f, 32, 64);
        if (l < 16) fpw[w * NU + tt * 16 + l] = f;
    }
    __syncthreads();

    for (int u = t; u < NU; u += 448) {
        float sacc = 0.f;
#pragma unroll
        for (int ww = 0; ww < 7; ++ww) sacc += fpw[ww * NU + u];
        fpPart[((size_t)d * NB + b) * NU + u] = sacc;
    }
}

// ---------------------------------------------------------------------------
// Phase 2c: out[b][u] = sum_d fpPart[d][b][u]
// ---------------------------------------------------------------------------
__global__ __launch_bounds__(512) void p2c_out(const float* __restrict__ fpPart,
                                               float* __restrict__ out)
{
    const int b = blockIdx.x, t = threadIdx.x;
    float s = 0.f;
#pragma unroll
    for (int d = 0; d <= ND; ++d) s += fpPart[((size_t)d * NB + b) * NU + t];
    out[(size_t)b * NU + t] = s;
}

// ---------------------------------------------------------------------------
extern "C" void kernel_launch(void* const* d_in, const int* in_sizes, int n_in,
                              void* d_out, int out_size, void* d_ws, size_t ws_size,
                              hipStream_t stream) {
    (void)in_sizes; (void)n_in; (void)out_size; (void)ws_size;
    const float* x        = (const float*)d_in[0];
    const float* W_inner  = (const float*)d_in[1];
    const float* b_inner  = (const float*)d_in[2];
    const float* W_output = (const float*)d_in[3];
    const float* b_output = (const float*)d_in[4];
    float* out = (float*)d_out;

    float* S0      = (float*)d_ws;                         // 409600 f32
    float* bonds   = S0 + SZ_S0;                           // 1280000 f32
    float* attrAll = bonds + SZ_BONDS;                     // 1638400 f32
    unsigned short* WBh = (unsigned short*)(attrAll + (size_t)NB * (ND + 1) * NA * KF);
    unsigned short* WBl = WBh + 65536;
    float* fpPart = bonds;                                 // overlay (bonds dead after p2a)

    p1_reduce<<<NB * NA, 256, 0, stream>>>(x, S0, attrAll, bonds);
    p2a_recur<<<NB * 2 + 16, 256, 0, stream>>>(S0, bonds, W_inner, b_inner, attrAll,
                                               W_output, WBh, WBl);

    const size_t smemB = 49152;                            // 48 KB -> 3 blocks/CU
    hipFuncSetAttribute(reinterpret_cast<const void*>(p2b_mfma),
                        hipFuncAttributeMaxDynamicSharedMemorySize, (int)smemB);
    p2b_mfma<<<NB * (ND + 1), 448, smemB, stream>>>(attrAll, WBh, WBl, b_output, fpPart);
    p2c_out<<<NB, 512, 0, stream>>>(fpPart, out);
}